// Round 9
// baseline (676.633 us; speedup 1.0000x reference)
//
#include <hip/hip_runtime.h>
#include <hip/hip_cooperative_groups.h>

namespace cg = cooperative_groups;

// DCRNN: 2x (node-sorted-gather SpMM -> fused MFMA GRU cell). N=50000, E=800000, D=64.
// CSR built in ONE cooperative kernel (atomic-free counting sort, LDS atomics only):
//   phase0: conv x/weights -> fp16 (blocks 196..1023) || per-block bucket hist (0..195)
//   phase1-3: exact exclusive scan of SC
//   phase4: place -> bucket-sorted (src|dl<<16, w-f16)
//   phase5: sort2 -> node-sorted pw[] (src:16 | w-f16:16) + off[]
// Then: aggr (wave/node, register acc, 8-deep gather) -> gru (fp16 MFMA), x2 layers.
#define NN 50000
#define NE 800000
#define DD 64
#define NT (NN / 16)      // 3125 node-tiles of 16
#define NBUK 1024         // dst buckets
#define BUCKN 49          // nodes per bucket: 1024*49 = 50176 >= 50000
#define EBLK 4096         // edges per binning block
#define NBBIN 196         // ceil(NE/EBLK)
#define SCN (NBUK * NBBIN)  // 200704 count cells
#define NSB 784           // SCN/256 scan chunks (exact)
#define CGB 1024          // cooperative grid blocks (4/CU: safe residency)

typedef float     f32x4 __attribute__((ext_vector_type(4)));
typedef _Float16  f16x8 __attribute__((ext_vector_type(8)));
typedef _Float16  f16x4 __attribute__((ext_vector_type(4)));

union h2u { _Float16 f; unsigned short u; };

// ---------------------------------------------------------------------------
// build: the whole CSR construction + fp16 conversion, one cooperative launch.
// LDS: 2048 u32 = 8KB, re-purposed per phase.
// ---------------------------------------------------------------------------
__global__ __launch_bounds__(256) void build_kernel(
    const float* __restrict__ x,
    const float* __restrict__ w0, const float* __restrict__ w1,
    const float* __restrict__ w2, const float* __restrict__ w3,
    _Float16* __restrict__ xh, _Float16* __restrict__ wh,
    const int* __restrict__ ei, const float* __restrict__ ew,
    unsigned* __restrict__ SC, unsigned* __restrict__ psum,
    unsigned* __restrict__ sp, _Float16* __restrict__ sw,
    unsigned* __restrict__ pw, int* __restrict__ off)
{
    cg::grid_group grid = cg::this_grid();
    __shared__ unsigned lds[2048];
    int blk = blockIdx.x, t = threadIdx.x;

    // ---- phase 0: hist (blocks 0..195) || conv grid-stride (196..1023) ----
    if (blk < NBBIN) {
        for (int i = t; i < NBUK; i += 256) lds[i] = 0;
        __syncthreads();
        int base = blk * EBLK;
        int lim = NE - base; if (lim > EBLK) lim = EBLK;
        for (int k = t; k < lim; k += 256) {
            unsigned dst = (unsigned)ei[NE + base + k];
            atomicAdd(&lds[dst / BUCKN], 1u);           // LDS atomic only
        }
        __syncthreads();
        for (int i = t; i < NBUK; i += 256)
            SC[i * NBBIN + blk] = lds[i];
    } else {
        const int XQ = NN * DD / 4;                     // 800000 quads
        const int TOTQ = XQ + 4 * 3072;                 // + weight quads
        for (int i = (blk - NBBIN) * 256 + t; i < TOTQ; i += (CGB - NBBIN) * 256) {
            if (i < XQ) {
                float4 v = ((const float4*)x)[i];
                f16x4 o = { (_Float16)v.x, (_Float16)v.y, (_Float16)v.z, (_Float16)v.w };
                ((f16x4*)xh)[i] = o;
            } else {
                int wi = i - XQ;
                int mat = wi / 3072, q = wi - mat * 3072;
                const float* s = mat == 0 ? w0 : mat == 1 ? w1 : mat == 2 ? w2 : w3;
                float4 v = ((const float4*)s)[q];
                f16x4 o = { (_Float16)v.x, (_Float16)v.y, (_Float16)v.z, (_Float16)v.w };
                ((f16x4*)(wh + mat * 12288))[q] = o;
            }
        }
    }
    grid.sync();

    // ---- phase 1: per-chunk reduction (chunk = blk < NSB) ----
    if (blk < NSB) {
        lds[t] = SC[blk * 256 + t];
        __syncthreads();
        for (int d = 128; d > 0; d >>= 1) {
            if (t < d) lds[t] += lds[t + d];
            __syncthreads();
        }
        if (t == 0) psum[blk] = lds[0];
    }
    grid.sync();

    // ---- phase 2: exclusive scan of psum[NSB] by block 0 ----
    if (blk == 0) {
        unsigned running = 0;
        for (int c = 0; c < (NSB + 255) / 256; ++c) {
            int i = c * 256 + t;
            unsigned v = (i < NSB) ? psum[i] : 0;
            lds[t] = v;
            __syncthreads();
            #pragma unroll
            for (int d = 1; d < 256; d <<= 1) {
                unsigned add = (t >= d) ? lds[t - d] : 0;
                __syncthreads();
                lds[t] += add;
                __syncthreads();
            }
            if (i < NSB) psum[i] = running + lds[t] - v;    // exclusive
            unsigned tot = lds[255];
            __syncthreads();
            running += tot;
        }
    }
    grid.sync();

    // ---- phase 3: per-chunk exclusive scan of SC in-place ----
    if (blk < NSB) {
        int i = blk * 256 + t;
        unsigned v = SC[i];
        lds[t] = v;
        __syncthreads();
        #pragma unroll
        for (int d = 1; d < 256; d <<= 1) {
            unsigned add = (t >= d) ? lds[t - d] : 0;
            __syncthreads();
            lds[t] += add;
            __syncthreads();
        }
        SC[i] = psum[blk] + lds[t] - v;
    }
    grid.sync();

    // ---- phase 4: place (blocks 0..195): bucket-sorted sp/sw ----
    if (blk < NBBIN) {
        unsigned* lbase = lds;          // [0..1023]
        unsigned* lcur  = lds + NBUK;   // [1024..2047]
        for (int i = t; i < NBUK; i += 256) {
            lbase[i] = SC[i * NBBIN + blk];
            lcur[i] = 0;
        }
        __syncthreads();
        int base = blk * EBLK;
        int lim = NE - base; if (lim > EBLK) lim = EBLK;
        for (int k = t; k < lim; k += 256) {
            int e = base + k;
            unsigned dst = (unsigned)ei[NE + e];
            unsigned buk = dst / BUCKN;
            unsigned dl  = dst - buk * BUCKN;
            unsigned r = atomicAdd(&lcur[buk], 1u);     // LDS atomic only
            unsigned pos = lbase[buk] + r;
            sp[pos] = (unsigned)ei[e] | (dl << 16);
            sw[pos] = (_Float16)ew[e];
        }
    }
    grid.sync();

    // ---- phase 5: sort2 (all blocks): node-sorted pw + off ----
    {
        unsigned* hist  = lds;          // [0..48]
        unsigned* nbase = lds + 256;    // [256..304]
        unsigned* cur   = lds + 512;    // [512..560]
        int b = blk;
        unsigned start = SC[b * NBBIN];
        unsigned end   = (b + 1 < NBUK) ? SC[(b + 1) * NBBIN] : NE;
        int cnt = (int)(end - start);
        if (t < BUCKN) { hist[t] = 0; cur[t] = 0; }
        __syncthreads();
        for (int k = t; k < cnt; k += 256)
            atomicAdd(&hist[sp[start + k] >> 16], 1u);  // LDS atomic
        __syncthreads();
        if (t == 0) {                                   // tiny serial scan (49)
            unsigned run = 0;
            for (int i = 0; i < BUCKN; ++i) { nbase[i] = run; run += hist[i]; }
        }
        __syncthreads();
        if (t < BUCKN)
            off[b * BUCKN + t] = (int)(start + nbase[t]);
        for (int k = t; k < cnt; k += 256) {
            unsigned v = sp[start + k];
            unsigned dl = v >> 16;
            unsigned r = atomicAdd(&cur[dl], 1u);       // LDS atomic
            h2u c; c.f = sw[start + k];
            pw[start + nbase[dl] + r] = (v & 0xFFFFu) | ((unsigned)c.u << 16);
        }
    }
}

// ---------------------------------------------------------------------------
// aggr: one wave per node, lane = d-channel, register accumulation, 8-deep
// gather pipeline, clamp-masked tail, 4B/edge payload. No atomics.
// ---------------------------------------------------------------------------
__global__ __launch_bounds__(256) void aggr_kernel(const int* __restrict__ off,
                                                   const unsigned* __restrict__ pw,
                                                   const _Float16* __restrict__ xh,
                                                   _Float16* __restrict__ aggrh) {
    int wv = (blockIdx.x * 256 + threadIdx.x) >> 6;
    if (wv >= NN) return;
    int lane = threadIdx.x & 63;
    int s = off[wv], e = off[wv + 1];
    int n = e - s;
    const unsigned* p = pw + s;
    float acc = 0.f;
    for (int i = 0; i < n; i += 8) {
        unsigned P[8];
        #pragma unroll
        for (int j = 0; j < 8; ++j) {
            int idx = (i + j < n) ? i + j : n - 1;      // clamped, always valid
            P[j] = p[idx];
        }
        float a[8], w[8];
        #pragma unroll
        for (int j = 0; j < 8; ++j) a[j] = (float)xh[(P[j] & 0xFFFFu) * DD + lane];
        #pragma unroll
        for (int j = 0; j < 8; ++j) {
            h2u c; c.u = (unsigned short)(P[j] >> 16);
            w[j] = (i + j < n) ? (float)c.f : 0.f;
        }
        #pragma unroll
        for (int j = 0; j < 8; ++j) acc += a[j] * w[j];
    }
    aggrh[wv * DD + lane] = (_Float16)acc;
}

// ---------------------------------------------------------------------------
// Fused GRU cell with fp16 MFMA. One wave per 16-node tile.
// A/B fragments use the SAME k mapping (8 contiguous per lane) -> result exact
// under any HW per-lane k permutation. C/D: col=lane&15, row=(lane>>4)*4+reg.
// ---------------------------------------------------------------------------
__global__ __launch_bounds__(256) void gru_kernel(
    const _Float16* __restrict__ aggrh,  // [N,64] fp16 (from aggregation)
    const _Float16* __restrict__ hA,     // [N,64] fp16: h (x or h1)
    const _Float16* __restrict__ wih,    // [192*64] fp16
    const _Float16* __restrict__ whh,    // [192*64] fp16
    const float* __restrict__ bih, const float* __restrict__ bhh,
    float* __restrict__ outF,            // layer2: d_out f32 (or null)
    _Float16* __restrict__ outH)         // layer1: h1 fp16 (or null)
{
    // Weights in LDS, rows padded 64->72 halves (144B: 16B-aligned, 2-way banks = free)
    __shared__ _Float16 W[2 * 192 * 72];
    #pragma unroll
    for (int it = 0; it < 12; ++it) {
        int idx = threadIdx.x + it * 256;          // 3072 vec8 = 2 mats * 192 rows * 8
        int mat = idx >= 1536 ? 1 : 0;
        int lid = idx - mat * 1536;
        int o = lid >> 3, k8 = (lid & 7) << 3;
        f16x8 v = *(const f16x8*)((mat ? whh : wih) + o * 64 + k8);
        *(f16x8*)&W[mat * 13824 + o * 72 + k8] = v;
    }
    __syncthreads();

    int lane = threadIdx.x & 63;
    int tile = blockIdx.x * 4 + (threadIdx.x >> 6);
    if (tile >= NT) return;
    int base = tile << 4;
    int c = lane & 15, g = lane >> 4;

    // A fragments: lane holds row (base+c), k = s*32 + g*8 .. +7
    f16x8 Aa[2], Ah[2];
    {
        const _Float16* ap = aggrh + (base + c) * DD + g * 8;
        const _Float16* hp = hA    + (base + c) * DD + g * 8;
        #pragma unroll
        for (int s = 0; s < 2; ++s) {
            Aa[s] = *(const f16x8*)(ap + s * 32);
            Ah[s] = *(const f16x8*)(hp + s * 32);
        }
    }

    f32x4 acc[12], hn[4];
    #pragma unroll
    for (int t = 0; t < 12; ++t) acc[t] = f32x4{0.f, 0.f, 0.f, 0.f};
    #pragma unroll
    for (int t = 0; t < 4; ++t) hn[t] = f32x4{0.f, 0.f, 0.f, 0.f};

    // gi for all 12 out-tiles (o = t*16+c)
    #pragma unroll
    for (int t = 0; t < 12; ++t) {
        #pragma unroll
        for (int s = 0; s < 2; ++s) {
            f16x8 b = *(const f16x8*)&W[(t * 16 + c) * 72 + s * 32 + g * 8];
            acc[t] = __builtin_amdgcn_mfma_f32_16x16x32_f16(Aa[s], b, acc[t], 0, 0, 0);
        }
    }
    // gh for r,z tiles (0..7): accumulate into the same acc (only sum needed)
    #pragma unroll
    for (int t = 0; t < 8; ++t) {
        #pragma unroll
        for (int s = 0; s < 2; ++s) {
            f16x8 b = *(const f16x8*)&W[13824 + (t * 16 + c) * 72 + s * 32 + g * 8];
            acc[t] = __builtin_amdgcn_mfma_f32_16x16x32_f16(Ah[s], b, acc[t], 0, 0, 0);
        }
    }
    // gh for n tiles (8..11): separate h_n
    #pragma unroll
    for (int t = 0; t < 4; ++t) {
        #pragma unroll
        for (int s = 0; s < 2; ++s) {
            f16x8 b = *(const f16x8*)&W[13824 + ((t + 8) * 16 + c) * 72 + s * 32 + g * 8];
            hn[t] = __builtin_amdgcn_mfma_f32_16x16x32_f16(Ah[s], b, hn[t], 0, 0, 0);
        }
    }

    // biases (lane-local, d = j*16 + c)
    float br[4], bz[4], bi_[4], bh_[4];
    #pragma unroll
    for (int j = 0; j < 4; ++j) {
        int d = j * 16 + c;
        br[j] = bih[d] + bhh[d];
        bz[j] = bih[64 + d] + bhh[64 + d];
        bi_[j] = bih[128 + d];
        bh_[j] = bhh[128 + d];
    }

    // gates + output. C layout: row (node) = g*4+m, col (d-slot) = c.
    #pragma unroll
    for (int m = 0; m < 4; ++m) {
        int n = base + g * 4 + m;
        #pragma unroll
        for (int j = 0; j < 4; ++j) {
            int d = j * 16 + c;
            float rv = 1.f / (1.f + __expf(-(acc[j][m] + br[j])));
            float zv = 1.f / (1.f + __expf(-(acc[4 + j][m] + bz[j])));
            float nv = tanhf(acc[8 + j][m] + bi_[j] + rv * (hn[j][m] + bh_[j]));
            float hold = (float)hA[n * DD + d];
            float o = (1.f - zv) * nv + zv * hold;
            if (outF) outF[n * DD + d] = o;
            else      outH[n * DD + d] = (_Float16)o;
        }
    }
}

// ---------------------------------------------------------------------------
extern "C" void kernel_launch(void* const* d_in, const int* in_sizes, int n_in,
                              void* d_out, int out_size, void* d_ws, size_t ws_size,
                              hipStream_t stream) {
    const float* x    = (const float*)d_in[0];
    const int*   ei   = (const int*)d_in[1];     // [2,E] int32
    const float* ew   = (const float*)d_in[2];   // [E,1]
    const float* wih1 = (const float*)d_in[3];
    const float* whh1 = (const float*)d_in[4];
    const float* bih1 = (const float*)d_in[5];
    const float* bhh1 = (const float*)d_in[6];
    const float* wih2 = (const float*)d_in[7];
    const float* whh2 = (const float*)d_in[8];
    const float* bih2 = (const float*)d_in[9];
    const float* bhh2 = (const float*)d_in[10];
    float* out = (float*)d_out;

    // workspace (total ~22.7MB). aggrh ALIASES the sp/sw/SC/psum pool —
    // those are dead once build_kernel completes (stream order).
    char* ws = (char*)d_ws;
    _Float16* xh    = (_Float16*)ws;
    _Float16* h1h   = (_Float16*)(ws + 6400000);
    unsigned* pw    = (unsigned*)(ws + 12800000);
    unsigned* sp    = (unsigned*)(ws + 16000000);
    _Float16* sw    = (_Float16*)(ws + 19200000);
    unsigned* SC    = (unsigned*)(ws + 20800000);
    unsigned* psum  = (unsigned*)(ws + 21602816);
    _Float16* aggrh = (_Float16*)(ws + 16000000);   // alias: live after build
    _Float16* wh    = (_Float16*)(ws + 22400000);
    int*      off   = (int*)     (ws + 22498304);

    // ---- build: conversion + full CSR construction, one cooperative launch
    void* args[] = {
        (void*)&x, (void*)&wih1, (void*)&whh1, (void*)&wih2, (void*)&whh2,
        (void*)&xh, (void*)&wh, (void*)&ei, (void*)&ew,
        (void*)&SC, (void*)&psum, (void*)&sp, (void*)&sw,
        (void*)&pw, (void*)&off
    };
    (void)hipLaunchCooperativeKernel((void*)build_kernel, dim3(CGB), dim3(256),
                                     args, 0, stream);

    // ---- layer 1 ----
    aggr_kernel<<<NN * 64 / 256, 256, 0, stream>>>(off, pw, xh, aggrh);
    gru_kernel<<<(NT + 3) / 4, 256, 0, stream>>>(aggrh, xh,
                                                 wh, wh + 12288, bih1, bhh1,
                                                 nullptr, h1h);

    // ---- layer 2 ----
    aggr_kernel<<<NN * 64 / 256, 256, 0, stream>>>(off, pw, h1h, aggrh);
    gru_kernel<<<(NT + 3) / 4, 256, 0, stream>>>(aggrh, h1h,
                                                 wh + 2 * 12288, wh + 3 * 12288, bih2, bhh2,
                                                 out, nullptr);
}

// Round 10
// 136.451 us; speedup vs baseline: 4.9588x; 4.9588x over previous
//
#include <hip/hip_runtime.h>

// DCRNN: 2x (node-sorted-gather SpMM -> fused MFMA GRU cell). N=50000, E=800000, D=64.
// CSR built via fully atomic-free two-pass counting sort (LDS atomics only):
//   prep: per-block LDS histogram over 1024 dst-buckets -> SC counts matrix
//   scan: exact exclusive scan of SC (3 small kernels; kernel boundary = cheap
//         global barrier — cooperative grid.sync measured ~100us/sync, round 9)
//   place: bucket-sorted (src | dst-local<<16, w) arrays, exclusive positions
//   sort2: within-bucket 49-bin sort -> node-sorted pw[] (src:16|w-f16:16) + off[]
//   aggr: one wave per node, register accumulation, 16-deep gather pipeline
#define NN 50000
#define NE 800000
#define DD 64
#define NT (NN / 16)      // 3125 node-tiles of 16
#define NBUK 1024         // dst buckets
#define BUCKN 49          // nodes per bucket: 1024*49 = 50176 >= 50000
#define EBLK 4096         // edges per binning block
#define NBBIN 196         // ceil(NE/EBLK)
#define SCN (NBUK * NBBIN)  // 200704 count cells
#define NSB 784           // SCN/256 scan blocks (exact)
#define CONVB 3173        // conversion blocks

typedef float     f32x4 __attribute__((ext_vector_type(4)));
typedef _Float16  f16x8 __attribute__((ext_vector_type(8)));
typedef _Float16  f16x4 __attribute__((ext_vector_type(4)));

union h2u { _Float16 f; unsigned short u; };

// ---------------------------------------------------------------------------
// prep: convert x f32->fp16 + 4 weight mats -> fp16  ||  per-block LDS
// histogram of dst buckets -> SC[buk*NBBIN + blk]. LDS atomics only.
// ---------------------------------------------------------------------------
__global__ void prep_kernel(const float* __restrict__ x,
                            const float* __restrict__ w0, const float* __restrict__ w1,
                            const float* __restrict__ w2, const float* __restrict__ w3,
                            _Float16* __restrict__ xh, _Float16* __restrict__ wh,
                            const int* __restrict__ ei, unsigned* __restrict__ SC) {
    if (blockIdx.x < CONVB) {
        int i = blockIdx.x * 256 + threadIdx.x; // quad index
        const int XQ = NN * DD / 4;             // 800000 quads of x
        if (i < XQ) {
            float4 v = ((const float4*)x)[i];
            f16x4 o = { (_Float16)v.x, (_Float16)v.y, (_Float16)v.z, (_Float16)v.w };
            ((f16x4*)xh)[i] = o;
        } else {
            int wi = i - XQ;                    // 4 mats * 3072 quads
            if (wi >= 4 * 3072) return;
            int mat = wi / 3072, q = wi - mat * 3072;
            const float* s = mat == 0 ? w0 : mat == 1 ? w1 : mat == 2 ? w2 : w3;
            float4 v = ((const float4*)s)[q];
            f16x4 o = { (_Float16)v.x, (_Float16)v.y, (_Float16)v.z, (_Float16)v.w };
            ((f16x4*)(wh + mat * 12288))[q] = o;
        }
    } else {
        int blk = blockIdx.x - CONVB;
        __shared__ unsigned lcnt[NBUK];
        for (int i = threadIdx.x; i < NBUK; i += 256) lcnt[i] = 0;
        __syncthreads();
        int base = blk * EBLK;
        int lim = NE - base; if (lim > EBLK) lim = EBLK;
        for (int k = threadIdx.x; k < lim; k += 256) {
            unsigned dst = (unsigned)ei[NE + base + k];
            atomicAdd(&lcnt[dst / BUCKN], 1u);          // LDS atomic (u32, native)
        }
        __syncthreads();
        for (int i = threadIdx.x; i < NBUK; i += 256)
            SC[i * NBBIN + blk] = lcnt[i];
    }
}

// ---------------------------------------------------------------------------
// Exact exclusive scan of SC[SCN] in-place (3 kernels).
// ---------------------------------------------------------------------------
__global__ void scan1_kernel(const unsigned* __restrict__ SC, unsigned* __restrict__ psum) {
    __shared__ unsigned red[256];
    int i = blockIdx.x * 256 + threadIdx.x;             // grid covers SCN exactly
    red[threadIdx.x] = SC[i];
    __syncthreads();
    for (int d = 128; d > 0; d >>= 1) {
        if (threadIdx.x < d) red[threadIdx.x] += red[threadIdx.x + d];
        __syncthreads();
    }
    if (threadIdx.x == 0) psum[blockIdx.x] = red[0];
}

__global__ void scan2_kernel(unsigned* __restrict__ psum) {
    __shared__ unsigned tmp[256];
    int t = threadIdx.x;
    unsigned running = 0;
    for (int c = 0; c < (NSB + 255) / 256; ++c) {
        int i = c * 256 + t;
        unsigned v = (i < NSB) ? psum[i] : 0;
        tmp[t] = v;
        __syncthreads();
        #pragma unroll
        for (int d = 1; d < 256; d <<= 1) {
            unsigned add = (t >= d) ? tmp[t - d] : 0;
            __syncthreads();
            tmp[t] += add;
            __syncthreads();
        }
        if (i < NSB) psum[i] = running + tmp[t] - v;    // exclusive
        unsigned tot = tmp[255];
        __syncthreads();
        running += tot;
    }
}

__global__ void scan3_kernel(unsigned* __restrict__ SC, const unsigned* __restrict__ psum) {
    __shared__ unsigned tmp[256];
    int t = threadIdx.x;
    int i = blockIdx.x * 256 + t;
    unsigned v = SC[i];
    tmp[t] = v;
    __syncthreads();
    #pragma unroll
    for (int d = 1; d < 256; d <<= 1) {
        unsigned add = (t >= d) ? tmp[t - d] : 0;
        __syncthreads();
        tmp[t] += add;
        __syncthreads();
    }
    SC[i] = psum[blockIdx.x] + tmp[t] - v;              // in-place exclusive
}

// ---------------------------------------------------------------------------
// place: bucket-sorted arrays via exclusive positions (LDS cursors only).
// sp u32 = src | (dl<<16) (src<2^16, dl<49), sw = f16 weight.
// ---------------------------------------------------------------------------
__global__ __launch_bounds__(256) void place_kernel(const int* __restrict__ ei,
                                                    const float* __restrict__ ew,
                                                    const unsigned* __restrict__ SC,
                                                    unsigned* __restrict__ sp,
                                                    _Float16* __restrict__ sw) {
    __shared__ unsigned lbase[NBUK];
    __shared__ unsigned lcur[NBUK];
    int blk = blockIdx.x;
    for (int i = threadIdx.x; i < NBUK; i += 256) {
        lbase[i] = SC[i * NBBIN + blk];
        lcur[i] = 0;
    }
    __syncthreads();
    int base = blk * EBLK;
    int lim = NE - base; if (lim > EBLK) lim = EBLK;
    for (int k = threadIdx.x; k < lim; k += 256) {
        int e = base + k;
        unsigned dst = (unsigned)ei[NE + e];
        unsigned buk = dst / BUCKN;
        unsigned dl  = dst - buk * BUCKN;
        unsigned r = atomicAdd(&lcur[buk], 1u);         // LDS atomic only
        unsigned pos = lbase[buk] + r;
        sp[pos] = (unsigned)ei[e] | (dl << 16);
        sw[pos] = (_Float16)ew[e];
    }
}

// ---------------------------------------------------------------------------
// sort2: one block per bucket. 49-bin LDS histogram + rank -> node-sorted
// packed edges pw[] = src | (f16-weight-bits << 16), and per-node off[].
// ---------------------------------------------------------------------------
__global__ __launch_bounds__(256) void sort2_kernel(const unsigned* __restrict__ SC,
                                                    const unsigned* __restrict__ sp,
                                                    const _Float16* __restrict__ sw,
                                                    unsigned* __restrict__ pw,
                                                    int* __restrict__ off) {
    __shared__ unsigned hist[BUCKN], nbase[BUCKN], cur[BUCKN];
    int b = blockIdx.x;
    unsigned start = SC[b * NBBIN];
    unsigned end   = (b + 1 < NBUK) ? SC[(b + 1) * NBBIN] : NE;
    int cnt = (int)(end - start);
    if (threadIdx.x < BUCKN) { hist[threadIdx.x] = 0; cur[threadIdx.x] = 0; }
    __syncthreads();
    for (int k = threadIdx.x; k < cnt; k += 256)
        atomicAdd(&hist[sp[start + k] >> 16], 1u);      // LDS atomic
    __syncthreads();
    if (threadIdx.x == 0) {                             // tiny serial scan (49)
        unsigned run = 0;
        for (int i = 0; i < BUCKN; ++i) { nbase[i] = run; run += hist[i]; }
    }
    __syncthreads();
    if (threadIdx.x < BUCKN)
        off[b * BUCKN + threadIdx.x] = (int)(start + nbase[threadIdx.x]);
    for (int k = threadIdx.x; k < cnt; k += 256) {
        unsigned v = sp[start + k];
        unsigned dl = v >> 16;
        unsigned r = atomicAdd(&cur[dl], 1u);           // LDS atomic
        h2u c; c.f = sw[start + k];
        pw[start + nbase[dl] + r] = (v & 0xFFFFu) | ((unsigned)c.u << 16);
    }
}

// ---------------------------------------------------------------------------
// aggr: one wave per node, lane = d-channel, register accumulation, 16-deep
// gather pipeline (degree ~ Poisson(16): ~55% of nodes finish in ONE round
// of independent loads vs 2-3 dependent rounds at depth 8). Clamp-masked
// tail, 4B/edge payload. No atomics.
// ---------------------------------------------------------------------------
__global__ __launch_bounds__(256) void aggr_kernel(const int* __restrict__ off,
                                                   const unsigned* __restrict__ pw,
                                                   const _Float16* __restrict__ xh,
                                                   _Float16* __restrict__ aggrh) {
    int wv = (blockIdx.x * 256 + threadIdx.x) >> 6;
    if (wv >= NN) return;
    int lane = threadIdx.x & 63;
    int s = off[wv], e = off[wv + 1];
    int n = e - s;
    const unsigned* p = pw + s;
    float acc = 0.f;
    for (int i = 0; i < n; i += 16) {
        unsigned P[16];
        #pragma unroll
        for (int j = 0; j < 16; ++j) {
            int idx = (i + j < n) ? i + j : n - 1;      // clamped, always valid
            P[j] = p[idx];
        }
        float a[16], w[16];
        #pragma unroll
        for (int j = 0; j < 16; ++j) a[j] = (float)xh[(P[j] & 0xFFFFu) * DD + lane];
        #pragma unroll
        for (int j = 0; j < 16; ++j) {
            h2u c; c.u = (unsigned short)(P[j] >> 16);
            w[j] = (i + j < n) ? (float)c.f : 0.f;
        }
        #pragma unroll
        for (int j = 0; j < 16; ++j) acc += a[j] * w[j];
    }
    aggrh[wv * DD + lane] = (_Float16)acc;
}

// ---------------------------------------------------------------------------
// Fused GRU cell with fp16 MFMA. One wave per 16-node tile.
// A/B fragments use the SAME k mapping (8 contiguous per lane) -> result exact
// under any HW per-lane k permutation. C/D: col=lane&15, row=(lane>>4)*4+reg.
// ---------------------------------------------------------------------------
__global__ __launch_bounds__(256) void gru_kernel(
    const _Float16* __restrict__ aggrh,  // [N,64] fp16 (from aggregation)
    const _Float16* __restrict__ hA,     // [N,64] fp16: h (x or h1)
    const _Float16* __restrict__ wih,    // [192*64] fp16
    const _Float16* __restrict__ whh,    // [192*64] fp16
    const float* __restrict__ bih, const float* __restrict__ bhh,
    float* __restrict__ outF,            // layer2: d_out f32 (or null)
    _Float16* __restrict__ outH)         // layer1: h1 fp16 (or null)
{
    // Weights in LDS, rows padded 64->72 halves (144B: 16B-aligned, 2-way banks = free)
    __shared__ _Float16 W[2 * 192 * 72];
    #pragma unroll
    for (int it = 0; it < 12; ++it) {
        int idx = threadIdx.x + it * 256;          // 3072 vec8 = 2 mats * 192 rows * 8
        int mat = idx >= 1536 ? 1 : 0;
        int lid = idx - mat * 1536;
        int o = lid >> 3, k8 = (lid & 7) << 3;
        f16x8 v = *(const f16x8*)((mat ? whh : wih) + o * 64 + k8);
        *(f16x8*)&W[mat * 13824 + o * 72 + k8] = v;
    }
    __syncthreads();

    int lane = threadIdx.x & 63;
    int tile = blockIdx.x * 4 + (threadIdx.x >> 6);
    if (tile >= NT) return;
    int base = tile << 4;
    int c = lane & 15, g = lane >> 4;

    // A fragments: lane holds row (base+c), k = s*32 + g*8 .. +7
    f16x8 Aa[2], Ah[2];
    {
        const _Float16* ap = aggrh + (base + c) * DD + g * 8;
        const _Float16* hp = hA    + (base + c) * DD + g * 8;
        #pragma unroll
        for (int s = 0; s < 2; ++s) {
            Aa[s] = *(const f16x8*)(ap + s * 32);
            Ah[s] = *(const f16x8*)(hp + s * 32);
        }
    }

    f32x4 acc[12], hn[4];
    #pragma unroll
    for (int t = 0; t < 12; ++t) acc[t] = f32x4{0.f, 0.f, 0.f, 0.f};
    #pragma unroll
    for (int t = 0; t < 4; ++t) hn[t] = f32x4{0.f, 0.f, 0.f, 0.f};

    // gi for all 12 out-tiles (o = t*16+c)
    #pragma unroll
    for (int t = 0; t < 12; ++t) {
        #pragma unroll
        for (int s = 0; s < 2; ++s) {
            f16x8 b = *(const f16x8*)&W[(t * 16 + c) * 72 + s * 32 + g * 8];
            acc[t] = __builtin_amdgcn_mfma_f32_16x16x32_f16(Aa[s], b, acc[t], 0, 0, 0);
        }
    }
    // gh for r,z tiles (0..7): accumulate into the same acc (only sum needed)
    #pragma unroll
    for (int t = 0; t < 8; ++t) {
        #pragma unroll
        for (int s = 0; s < 2; ++s) {
            f16x8 b = *(const f16x8*)&W[13824 + (t * 16 + c) * 72 + s * 32 + g * 8];
            acc[t] = __builtin_amdgcn_mfma_f32_16x16x32_f16(Ah[s], b, acc[t], 0, 0, 0);
        }
    }
    // gh for n tiles (8..11): separate h_n
    #pragma unroll
    for (int t = 0; t < 4; ++t) {
        #pragma unroll
        for (int s = 0; s < 2; ++s) {
            f16x8 b = *(const f16x8*)&W[13824 + ((t + 8) * 16 + c) * 72 + s * 32 + g * 8];
            hn[t] = __builtin_amdgcn_mfma_f32_16x16x32_f16(Ah[s], b, hn[t], 0, 0, 0);
        }
    }

    // biases (lane-local, d = j*16 + c)
    float br[4], bz[4], bi_[4], bh_[4];
    #pragma unroll
    for (int j = 0; j < 4; ++j) {
        int d = j * 16 + c;
        br[j] = bih[d] + bhh[d];
        bz[j] = bih[64 + d] + bhh[64 + d];
        bi_[j] = bih[128 + d];
        bh_[j] = bhh[128 + d];
    }

    // gates + output. C layout: row (node) = g*4+m, col (d-slot) = c.
    #pragma unroll
    for (int m = 0; m < 4; ++m) {
        int n = base + g * 4 + m;
        #pragma unroll
        for (int j = 0; j < 4; ++j) {
            int d = j * 16 + c;
            float rv = 1.f / (1.f + __expf(-(acc[j][m] + br[j])));
            float zv = 1.f / (1.f + __expf(-(acc[4 + j][m] + bz[j])));
            float nv = tanhf(acc[8 + j][m] + bi_[j] + rv * (hn[j][m] + bh_[j]));
            float hold = (float)hA[n * DD + d];
            float o = (1.f - zv) * nv + zv * hold;
            if (outF) outF[n * DD + d] = o;
            else      outH[n * DD + d] = (_Float16)o;
        }
    }
}

// ---------------------------------------------------------------------------
extern "C" void kernel_launch(void* const* d_in, const int* in_sizes, int n_in,
                              void* d_out, int out_size, void* d_ws, size_t ws_size,
                              hipStream_t stream) {
    const float* x    = (const float*)d_in[0];
    const int*   ei   = (const int*)d_in[1];     // [2,E] int32
    const float* ew   = (const float*)d_in[2];   // [E,1]
    const float* wih1 = (const float*)d_in[3];
    const float* whh1 = (const float*)d_in[4];
    const float* bih1 = (const float*)d_in[5];
    const float* bhh1 = (const float*)d_in[6];
    const float* wih2 = (const float*)d_in[7];
    const float* whh2 = (const float*)d_in[8];
    const float* bih2 = (const float*)d_in[9];
    const float* bhh2 = (const float*)d_in[10];
    float* out = (float*)d_out;

    // workspace (total ~22.7MB). aggrh ALIASES the sp/sw/SC/psum pool —
    // those are dead once sort2 completes (stream order).
    char* ws = (char*)d_ws;
    _Float16* xh    = (_Float16*)ws;
    _Float16* h1h   = (_Float16*)(ws + 6400000);
    unsigned* pw    = (unsigned*)(ws + 12800000);
    unsigned* sp    = (unsigned*)(ws + 16000000);
    _Float16* sw    = (_Float16*)(ws + 19200000);
    unsigned* SC    = (unsigned*)(ws + 20800000);
    unsigned* psum  = (unsigned*)(ws + 21602816);
    _Float16* aggrh = (_Float16*)(ws + 16000000);   // alias: live after sort2
    _Float16* wh    = (_Float16*)(ws + 22400000);
    int*      off   = (int*)     (ws + 22498304);

    // convert (x + weights -> fp16) || per-block bucket histogram. No memsets.
    prep_kernel<<<CONVB + NBBIN, 256, 0, stream>>>(x, wih1, whh1, wih2, whh2,
                                                   xh, wh, ei, SC);
    // exact exclusive scan of SC (in-place)
    scan1_kernel<<<NSB, 256, 0, stream>>>(SC, psum);
    scan2_kernel<<<1, 256, 0, stream>>>(psum);
    scan3_kernel<<<NSB, 256, 0, stream>>>(SC, psum);
    // bucket-sorted placement, then within-bucket node sort -> pw/off
    place_kernel<<<NBBIN, 256, 0, stream>>>(ei, ew, SC, sp, sw);
    sort2_kernel<<<NBUK, 256, 0, stream>>>(SC, sp, sw, pw, off);

    // ---- layer 1 ----
    aggr_kernel<<<NN * 64 / 256, 256, 0, stream>>>(off, pw, xh, aggrh);
    gru_kernel<<<(NT + 3) / 4, 256, 0, stream>>>(aggrh, xh,
                                                 wh, wh + 12288, bih1, bhh1,
                                                 nullptr, h1h);

    // ---- layer 2 ----
    aggr_kernel<<<NN * 64 / 256, 256, 0, stream>>>(off, pw, h1h, aggrh);
    gru_kernel<<<(NT + 3) / 4, 256, 0, stream>>>(aggrh, h1h,
                                                 wh + 2 * 12288, wh + 3 * 12288, bih2, bhh2,
                                                 out, nullptr);
}

// Round 11
// 130.567 us; speedup vs baseline: 5.1823x; 1.0451x over previous
//
#include <hip/hip_runtime.h>

// DCRNN: 2x (node-sorted-gather SpMM -> fused MFMA GRU cell). N=50000, E=800000, D=64.
// CSR built via fully atomic-free two-pass counting sort (LDS atomics only):
//   prep: per-block LDS histogram over 1024 dst-buckets -> SC counts matrix
//         (+ zeroes the scan status array each call)
//   scan: ONE decoupled-lookback kernel (packed u64 status word; 784 blocks all
//         co-resident -> spin-free-ish, no deadlock; replaces 3-kernel chain —
//         single-block scan2 alone cost ~5us dispatch ramp)
//   place: bucket-sorted (src | dst-local<<16, w) arrays, exclusive positions
//   sort2: within-bucket 49-bin sort -> node-sorted pw[] (src:16|w-f16:16) + off[]
//   aggr: one wave per node, register accumulation, 8-deep gather pipeline
//         (depth 16 measured neutral-negative in r10 -> reverted to proven r8)
#define NN 50000
#define NE 800000
#define DD 64
#define NT (NN / 16)      // 3125 node-tiles of 16
#define NBUK 1024         // dst buckets
#define BUCKN 49          // nodes per bucket: 1024*49 = 50176 >= 50000
#define EBLK 4096         // edges per binning block
#define NBBIN 196         // ceil(NE/EBLK)
#define SCN (NBUK * NBBIN)  // 200704 count cells
#define NSB 784           // SCN/256 scan blocks (exact)
#define CONVB 3173        // conversion blocks

typedef float     f32x4 __attribute__((ext_vector_type(4)));
typedef _Float16  f16x8 __attribute__((ext_vector_type(8)));
typedef _Float16  f16x4 __attribute__((ext_vector_type(4)));

union h2u { _Float16 f; unsigned short u; };

// ---------------------------------------------------------------------------
// prep: convert x f32->fp16 + 4 weight mats -> fp16  ||  per-block LDS
// histogram of dst buckets -> SC[buk*NBBIN + blk]. LDS atomics only.
// Hist block 0 also zeroes the lookback status array (replay-safe re-init).
// ---------------------------------------------------------------------------
__global__ void prep_kernel(const float* __restrict__ x,
                            const float* __restrict__ w0, const float* __restrict__ w1,
                            const float* __restrict__ w2, const float* __restrict__ w3,
                            _Float16* __restrict__ xh, _Float16* __restrict__ wh,
                            const int* __restrict__ ei, unsigned* __restrict__ SC,
                            unsigned long long* __restrict__ st) {
    if (blockIdx.x < CONVB) {
        int i = blockIdx.x * 256 + threadIdx.x; // quad index
        const int XQ = NN * DD / 4;             // 800000 quads of x
        if (i < XQ) {
            float4 v = ((const float4*)x)[i];
            f16x4 o = { (_Float16)v.x, (_Float16)v.y, (_Float16)v.z, (_Float16)v.w };
            ((f16x4*)xh)[i] = o;
        } else {
            int wi = i - XQ;                    // 4 mats * 3072 quads
            if (wi >= 4 * 3072) return;
            int mat = wi / 3072, q = wi - mat * 3072;
            const float* s = mat == 0 ? w0 : mat == 1 ? w1 : mat == 2 ? w2 : w3;
            float4 v = ((const float4*)s)[q];
            f16x4 o = { (_Float16)v.x, (_Float16)v.y, (_Float16)v.z, (_Float16)v.w };
            ((f16x4*)(wh + mat * 12288))[q] = o;
        }
    } else {
        int blk = blockIdx.x - CONVB;
        __shared__ unsigned lcnt[NBUK];
        if (blk == 0)                                   // re-zero scan status
            for (int i = threadIdx.x; i < NSB; i += 256) st[i] = 0ull;
        for (int i = threadIdx.x; i < NBUK; i += 256) lcnt[i] = 0;
        __syncthreads();
        int base = blk * EBLK;
        int lim = NE - base; if (lim > EBLK) lim = EBLK;
        for (int k = threadIdx.x; k < lim; k += 256) {
            unsigned dst = (unsigned)ei[NE + base + k];
            atomicAdd(&lcnt[dst / BUCKN], 1u);          // LDS atomic (u32, native)
        }
        __syncthreads();
        for (int i = threadIdx.x; i < NBUK; i += 256)
            SC[i * NBBIN + blk] = lcnt[i];
    }
}

// ---------------------------------------------------------------------------
// Single-kernel decoupled-lookback exclusive scan of SC[SCN] in-place.
// st[b] = (flag<<32)|value; flag: 0=invalid, 1=aggregate, 2=inclusive prefix.
// Single-word publish -> no producer fence needed. 784 blocks co-resident
// (<= 2048 capacity) -> lookback always terminates. Wave-0 windowed lookback.
// ---------------------------------------------------------------------------
__global__ __launch_bounds__(256) void scan_kernel(unsigned* __restrict__ SC,
                                                   unsigned long long* __restrict__ st) {
    __shared__ unsigned lds[256];
    __shared__ unsigned s_exc;
    int b = blockIdx.x, t = threadIdx.x;
    int i = b * 256 + t;
    unsigned v = SC[i];
    lds[t] = v;
    __syncthreads();
    #pragma unroll
    for (int d = 1; d < 256; d <<= 1) {                 // Hillis-Steele inclusive
        unsigned add = (t >= d) ? lds[t - d] : 0;
        __syncthreads();
        lds[t] += add;
        __syncthreads();
    }
    unsigned aggregate = lds[255];
    if (t == 0) {
        unsigned long long val = (b == 0) ? ((2ull << 32) | aggregate)
                                          : ((1ull << 32) | aggregate);
        __atomic_store_n(&st[b], val, __ATOMIC_RELAXED);
    }
    if (b > 0) {
        if (t < 64) {                                   // wave-0 windowed lookback
            unsigned run = 0;
            int p = b - 1;
            for (;;) {
                int idx = p - t;                        // lane 0 = closest pred
                unsigned f, val;
                unsigned long long m2, m0;
                int l2;
                for (;;) {                              // retry until consistent
                    if (idx >= 0) {
                        unsigned long long w =
                            __atomic_load_n(&st[idx], __ATOMIC_RELAXED);
                        f = (unsigned)(w >> 32);
                        val = (unsigned)w;
                    } else { f = 2u; val = 0u; }
                    m2 = __ballot(f == 2u);
                    m0 = __ballot(f == 0u);
                    l2 = (m2 != 0ull) ? (__ffsll((long long)m2) - 1) : 64;
                    unsigned long long below =
                        (l2 >= 64) ? ~0ull : ((1ull << l2) - 1ull);
                    if ((m0 & below) == 0ull) break;    // window consistent
                }
                unsigned contrib = (t <= l2 && idx >= 0) ? val : 0u;
                #pragma unroll
                for (int s = 32; s > 0; s >>= 1)
                    contrib += __shfl_xor(contrib, s, 64);
                run += contrib;                         // uniform across lanes
                if (l2 < 64) break;                     // hit an inclusive prefix
                p -= 64;
            }
            if (t == 0) {
                s_exc = run;
                __atomic_store_n(&st[b], (2ull << 32) | (run + aggregate),
                                 __ATOMIC_RELAXED);
            }
        }
        __syncthreads();
    }
    unsigned exc = (b == 0) ? 0u : s_exc;
    SC[i] = exc + lds[t] - v;                           // global exclusive
}

// ---------------------------------------------------------------------------
// place: bucket-sorted arrays via exclusive positions (LDS cursors only).
// sp u32 = src | (dl<<16) (src<2^16, dl<49), sw = f16 weight.
// ---------------------------------------------------------------------------
__global__ __launch_bounds__(256) void place_kernel(const int* __restrict__ ei,
                                                    const float* __restrict__ ew,
                                                    const unsigned* __restrict__ SC,
                                                    unsigned* __restrict__ sp,
                                                    _Float16* __restrict__ sw) {
    __shared__ unsigned lbase[NBUK];
    __shared__ unsigned lcur[NBUK];
    int blk = blockIdx.x;
    for (int i = threadIdx.x; i < NBUK; i += 256) {
        lbase[i] = SC[i * NBBIN + blk];
        lcur[i] = 0;
    }
    __syncthreads();
    int base = blk * EBLK;
    int lim = NE - base; if (lim > EBLK) lim = EBLK;
    for (int k = threadIdx.x; k < lim; k += 256) {
        int e = base + k;
        unsigned dst = (unsigned)ei[NE + e];
        unsigned buk = dst / BUCKN;
        unsigned dl  = dst - buk * BUCKN;
        unsigned r = atomicAdd(&lcur[buk], 1u);         // LDS atomic only
        unsigned pos = lbase[buk] + r;
        sp[pos] = (unsigned)ei[e] | (dl << 16);
        sw[pos] = (_Float16)ew[e];
    }
}

// ---------------------------------------------------------------------------
// sort2: one block per bucket. 49-bin LDS histogram + rank -> node-sorted
// packed edges pw[] = src | (f16-weight-bits << 16), and per-node off[].
// ---------------------------------------------------------------------------
__global__ __launch_bounds__(256) void sort2_kernel(const unsigned* __restrict__ SC,
                                                    const unsigned* __restrict__ sp,
                                                    const _Float16* __restrict__ sw,
                                                    unsigned* __restrict__ pw,
                                                    int* __restrict__ off) {
    __shared__ unsigned hist[BUCKN], nbase[BUCKN], cur[BUCKN];
    int b = blockIdx.x;
    unsigned start = SC[b * NBBIN];
    unsigned end   = (b + 1 < NBUK) ? SC[(b + 1) * NBBIN] : NE;
    int cnt = (int)(end - start);
    if (threadIdx.x < BUCKN) { hist[threadIdx.x] = 0; cur[threadIdx.x] = 0; }
    __syncthreads();
    for (int k = threadIdx.x; k < cnt; k += 256)
        atomicAdd(&hist[sp[start + k] >> 16], 1u);      // LDS atomic
    __syncthreads();
    if (threadIdx.x == 0) {                             // tiny serial scan (49)
        unsigned run = 0;
        for (int i = 0; i < BUCKN; ++i) { nbase[i] = run; run += hist[i]; }
    }
    __syncthreads();
    if (threadIdx.x < BUCKN)
        off[b * BUCKN + threadIdx.x] = (int)(start + nbase[threadIdx.x]);
    for (int k = threadIdx.x; k < cnt; k += 256) {
        unsigned v = sp[start + k];
        unsigned dl = v >> 16;
        unsigned r = atomicAdd(&cur[dl], 1u);           // LDS atomic
        h2u c; c.f = sw[start + k];
        pw[start + nbase[dl] + r] = (v & 0xFFFFu) | ((unsigned)c.u << 16);
    }
}

// ---------------------------------------------------------------------------
// aggr: one wave per node, lane = d-channel, register accumulation, 8-deep
// gather pipeline (r8-proven; depth 16 measured neutral-negative in r10).
// Clamp-masked tail, 4B/edge payload. No atomics.
// ---------------------------------------------------------------------------
__global__ __launch_bounds__(256) void aggr_kernel(const int* __restrict__ off,
                                                   const unsigned* __restrict__ pw,
                                                   const _Float16* __restrict__ xh,
                                                   _Float16* __restrict__ aggrh) {
    int wv = (blockIdx.x * 256 + threadIdx.x) >> 6;
    if (wv >= NN) return;
    int lane = threadIdx.x & 63;
    int s = off[wv], e = off[wv + 1];
    int n = e - s;
    const unsigned* p = pw + s;
    float acc = 0.f;
    for (int i = 0; i < n; i += 8) {
        unsigned P[8];
        #pragma unroll
        for (int j = 0; j < 8; ++j) {
            int idx = (i + j < n) ? i + j : n - 1;      // clamped, always valid
            P[j] = p[idx];
        }
        float a[8], w[8];
        #pragma unroll
        for (int j = 0; j < 8; ++j) a[j] = (float)xh[(P[j] & 0xFFFFu) * DD + lane];
        #pragma unroll
        for (int j = 0; j < 8; ++j) {
            h2u c; c.u = (unsigned short)(P[j] >> 16);
            w[j] = (i + j < n) ? (float)c.f : 0.f;
        }
        #pragma unroll
        for (int j = 0; j < 8; ++j) acc += a[j] * w[j];
    }
    aggrh[wv * DD + lane] = (_Float16)acc;
}

// ---------------------------------------------------------------------------
// Fused GRU cell with fp16 MFMA. One wave per 16-node tile.
// A/B fragments use the SAME k mapping (8 contiguous per lane) -> result exact
// under any HW per-lane k permutation. C/D: col=lane&15, row=(lane>>4)*4+reg.
// ---------------------------------------------------------------------------
__global__ __launch_bounds__(256) void gru_kernel(
    const _Float16* __restrict__ aggrh,  // [N,64] fp16 (from aggregation)
    const _Float16* __restrict__ hA,     // [N,64] fp16: h (x or h1)
    const _Float16* __restrict__ wih,    // [192*64] fp16
    const _Float16* __restrict__ whh,    // [192*64] fp16
    const float* __restrict__ bih, const float* __restrict__ bhh,
    float* __restrict__ outF,            // layer2: d_out f32 (or null)
    _Float16* __restrict__ outH)         // layer1: h1 fp16 (or null)
{
    // Weights in LDS, rows padded 64->72 halves (144B: 16B-aligned, 2-way banks = free)
    __shared__ _Float16 W[2 * 192 * 72];
    #pragma unroll
    for (int it = 0; it < 12; ++it) {
        int idx = threadIdx.x + it * 256;          // 3072 vec8 = 2 mats * 192 rows * 8
        int mat = idx >= 1536 ? 1 : 0;
        int lid = idx - mat * 1536;
        int o = lid >> 3, k8 = (lid & 7) << 3;
        f16x8 v = *(const f16x8*)((mat ? whh : wih) + o * 64 + k8);
        *(f16x8*)&W[mat * 13824 + o * 72 + k8] = v;
    }
    __syncthreads();

    int lane = threadIdx.x & 63;
    int tile = blockIdx.x * 4 + (threadIdx.x >> 6);
    if (tile >= NT) return;
    int base = tile << 4;
    int c = lane & 15, g = lane >> 4;

    // A fragments: lane holds row (base+c), k = s*32 + g*8 .. +7
    f16x8 Aa[2], Ah[2];
    {
        const _Float16* ap = aggrh + (base + c) * DD + g * 8;
        const _Float16* hp = hA    + (base + c) * DD + g * 8;
        #pragma unroll
        for (int s = 0; s < 2; ++s) {
            Aa[s] = *(const f16x8*)(ap + s * 32);
            Ah[s] = *(const f16x8*)(hp + s * 32);
        }
    }

    f32x4 acc[12], hn[4];
    #pragma unroll
    for (int t = 0; t < 12; ++t) acc[t] = f32x4{0.f, 0.f, 0.f, 0.f};
    #pragma unroll
    for (int t = 0; t < 4; ++t) hn[t] = f32x4{0.f, 0.f, 0.f, 0.f};

    // gi for all 12 out-tiles (o = t*16+c)
    #pragma unroll
    for (int t = 0; t < 12; ++t) {
        #pragma unroll
        for (int s = 0; s < 2; ++s) {
            f16x8 b = *(const f16x8*)&W[(t * 16 + c) * 72 + s * 32 + g * 8];
            acc[t] = __builtin_amdgcn_mfma_f32_16x16x32_f16(Aa[s], b, acc[t], 0, 0, 0);
        }
    }
    // gh for r,z tiles (0..7): accumulate into the same acc (only sum needed)
    #pragma unroll
    for (int t = 0; t < 8; ++t) {
        #pragma unroll
        for (int s = 0; s < 2; ++s) {
            f16x8 b = *(const f16x8*)&W[13824 + (t * 16 + c) * 72 + s * 32 + g * 8];
            acc[t] = __builtin_amdgcn_mfma_f32_16x16x32_f16(Ah[s], b, acc[t], 0, 0, 0);
        }
    }
    // gh for n tiles (8..11): separate h_n
    #pragma unroll
    for (int t = 0; t < 4; ++t) {
        #pragma unroll
        for (int s = 0; s < 2; ++s) {
            f16x8 b = *(const f16x8*)&W[13824 + ((t + 8) * 16 + c) * 72 + s * 32 + g * 8];
            hn[t] = __builtin_amdgcn_mfma_f32_16x16x32_f16(Ah[s], b, hn[t], 0, 0, 0);
        }
    }

    // biases (lane-local, d = j*16 + c)
    float br[4], bz[4], bi_[4], bh_[4];
    #pragma unroll
    for (int j = 0; j < 4; ++j) {
        int d = j * 16 + c;
        br[j] = bih[d] + bhh[d];
        bz[j] = bih[64 + d] + bhh[64 + d];
        bi_[j] = bih[128 + d];
        bh_[j] = bhh[128 + d];
    }

    // gates + output. C layout: row (node) = g*4+m, col (d-slot) = c.
    #pragma unroll
    for (int m = 0; m < 4; ++m) {
        int n = base + g * 4 + m;
        #pragma unroll
        for (int j = 0; j < 4; ++j) {
            int d = j * 16 + c;
            float rv = 1.f / (1.f + __expf(-(acc[j][m] + br[j])));
            float zv = 1.f / (1.f + __expf(-(acc[4 + j][m] + bz[j])));
            float nv = tanhf(acc[8 + j][m] + bi_[j] + rv * (hn[j][m] + bh_[j]));
            float hold = (float)hA[n * DD + d];
            float o = (1.f - zv) * nv + zv * hold;
            if (outF) outF[n * DD + d] = o;
            else      outH[n * DD + d] = (_Float16)o;
        }
    }
}

// ---------------------------------------------------------------------------
extern "C" void kernel_launch(void* const* d_in, const int* in_sizes, int n_in,
                              void* d_out, int out_size, void* d_ws, size_t ws_size,
                              hipStream_t stream) {
    const float* x    = (const float*)d_in[0];
    const int*   ei   = (const int*)d_in[1];     // [2,E] int32
    const float* ew   = (const float*)d_in[2];   // [E,1]
    const float* wih1 = (const float*)d_in[3];
    const float* whh1 = (const float*)d_in[4];
    const float* bih1 = (const float*)d_in[5];
    const float* bhh1 = (const float*)d_in[6];
    const float* wih2 = (const float*)d_in[7];
    const float* whh2 = (const float*)d_in[8];
    const float* bih2 = (const float*)d_in[9];
    const float* bhh2 = (const float*)d_in[10];
    float* out = (float*)d_out;

    // workspace (total ~22.7MB). aggrh ALIASES the sp/sw/SC/st pool —
    // those are dead once sort2 completes (stream order).
    char* ws = (char*)d_ws;
    _Float16* xh    = (_Float16*)ws;
    _Float16* h1h   = (_Float16*)(ws + 6400000);
    unsigned* pw    = (unsigned*)(ws + 12800000);
    unsigned* sp    = (unsigned*)(ws + 16000000);
    _Float16* sw    = (_Float16*)(ws + 19200000);
    unsigned* SC    = (unsigned*)(ws + 20800000);
    unsigned long long* st = (unsigned long long*)(ws + 21602816);  // 784 x 8B
    _Float16* aggrh = (_Float16*)(ws + 16000000);   // alias: live after sort2
    _Float16* wh    = (_Float16*)(ws + 22400000);
    int*      off   = (int*)     (ws + 22498304);

    // convert (x + weights -> fp16) || per-block bucket histogram (+st zero)
    prep_kernel<<<CONVB + NBBIN, 256, 0, stream>>>(x, wih1, whh1, wih2, whh2,
                                                   xh, wh, ei, SC, st);
    // single-kernel decoupled-lookback exclusive scan of SC (in-place)
    scan_kernel<<<NSB, 256, 0, stream>>>(SC, st);
    // bucket-sorted placement, then within-bucket node sort -> pw/off
    place_kernel<<<NBBIN, 256, 0, stream>>>(ei, ew, SC, sp, sw);
    sort2_kernel<<<NBUK, 256, 0, stream>>>(SC, sp, sw, pw, off);

    // ---- layer 1 ----
    aggr_kernel<<<NN * 64 / 256, 256, 0, stream>>>(off, pw, xh, aggrh);
    gru_kernel<<<(NT + 3) / 4, 256, 0, stream>>>(aggrh, xh,
                                                 wh, wh + 12288, bih1, bhh1,
                                                 nullptr, h1h);

    // ---- layer 2 ----
    aggr_kernel<<<NN * 64 / 256, 256, 0, stream>>>(off, pw, h1h, aggrh);
    gru_kernel<<<(NT + 3) / 4, 256, 0, stream>>>(aggrh, h1h,
                                                 wh + 2 * 12288, wh + 3 * 12288, bih2, bhh2,
                                                 out, nullptr);
}

// Round 12
// 122.530 us; speedup vs baseline: 5.5222x; 1.0656x over previous
//
#include <hip/hip_runtime.h>

// DCRNN: 2x (node-sorted-gather SpMM -> fused MFMA GRU cell). N=50000, E=800000, D=64.
// CSR built via fully atomic-free two-pass counting sort (LDS atomics only):
//   prep: per-block LDS histogram over 1024 dst-buckets -> SC counts matrix
//         (+ zeroes the scan status array each call)
//   scan: ONE decoupled-lookback kernel (packed u64 status word; 784 blocks all
//         co-resident -> no deadlock; 3-kernel chain cost ~12us, this ~4us)
//   place: bucket-sorted (src | dst-local<<16, w) arrays, exclusive positions
//   sort2: within-bucket 49-bin sort -> node-sorted pw[] (src:16|w-f16:16) + off[]
//   aggr: one wave per node, PAIRED-EDGE u32 gathers (lane = channel pair,
//         wave halves = edge parity): 16 edges per dependent round at depth-8
//         VGPR cost, half the gather instructions, v_fma_mix f32 accumulate.
#define NN 50000
#define NE 800000
#define DD 64
#define NT (NN / 16)      // 3125 node-tiles of 16
#define NBUK 1024         // dst buckets
#define BUCKN 49          // nodes per bucket: 1024*49 = 50176 >= 50000
#define EBLK 4096         // edges per binning block
#define NBBIN 196         // ceil(NE/EBLK)
#define SCN (NBUK * NBBIN)  // 200704 count cells
#define NSB 784           // SCN/256 scan blocks (exact)
#define CONVB 3173        // conversion blocks

typedef float     f32x4 __attribute__((ext_vector_type(4)));
typedef _Float16  f16x8 __attribute__((ext_vector_type(8)));
typedef _Float16  f16x4 __attribute__((ext_vector_type(4)));
typedef _Float16  f16x2 __attribute__((ext_vector_type(2)));

union h2u { _Float16 f; unsigned short u; };

// ---------------------------------------------------------------------------
// prep: convert x f32->fp16 + 4 weight mats -> fp16  ||  per-block LDS
// histogram of dst buckets -> SC[buk*NBBIN + blk]. LDS atomics only.
// Hist block 0 also zeroes the lookback status array (replay-safe re-init).
// ---------------------------------------------------------------------------
__global__ void prep_kernel(const float* __restrict__ x,
                            const float* __restrict__ w0, const float* __restrict__ w1,
                            const float* __restrict__ w2, const float* __restrict__ w3,
                            _Float16* __restrict__ xh, _Float16* __restrict__ wh,
                            const int* __restrict__ ei, unsigned* __restrict__ SC,
                            unsigned long long* __restrict__ st) {
    if (blockIdx.x < CONVB) {
        int i = blockIdx.x * 256 + threadIdx.x; // quad index
        const int XQ = NN * DD / 4;             // 800000 quads of x
        if (i < XQ) {
            float4 v = ((const float4*)x)[i];
            f16x4 o = { (_Float16)v.x, (_Float16)v.y, (_Float16)v.z, (_Float16)v.w };
            ((f16x4*)xh)[i] = o;
        } else {
            int wi = i - XQ;                    // 4 mats * 3072 quads
            if (wi >= 4 * 3072) return;
            int mat = wi / 3072, q = wi - mat * 3072;
            const float* s = mat == 0 ? w0 : mat == 1 ? w1 : mat == 2 ? w2 : w3;
            float4 v = ((const float4*)s)[q];
            f16x4 o = { (_Float16)v.x, (_Float16)v.y, (_Float16)v.z, (_Float16)v.w };
            ((f16x4*)(wh + mat * 12288))[q] = o;
        }
    } else {
        int blk = blockIdx.x - CONVB;
        __shared__ unsigned lcnt[NBUK];
        if (blk == 0)                                   // re-zero scan status
            for (int i = threadIdx.x; i < NSB; i += 256) st[i] = 0ull;
        for (int i = threadIdx.x; i < NBUK; i += 256) lcnt[i] = 0;
        __syncthreads();
        int base = blk * EBLK;
        int lim = NE - base; if (lim > EBLK) lim = EBLK;
        for (int k = threadIdx.x; k < lim; k += 256) {
            unsigned dst = (unsigned)ei[NE + base + k];
            atomicAdd(&lcnt[dst / BUCKN], 1u);          // LDS atomic (u32, native)
        }
        __syncthreads();
        for (int i = threadIdx.x; i < NBUK; i += 256)
            SC[i * NBBIN + blk] = lcnt[i];
    }
}

// ---------------------------------------------------------------------------
// Single-kernel decoupled-lookback exclusive scan of SC[SCN] in-place.
// st[b] = (flag<<32)|value; flag: 0=invalid, 1=aggregate, 2=inclusive prefix.
// Single-word publish -> no producer fence needed. 784 blocks co-resident
// (<= 2048 capacity) -> lookback always terminates. Wave-0 windowed lookback.
// ---------------------------------------------------------------------------
__global__ __launch_bounds__(256) void scan_kernel(unsigned* __restrict__ SC,
                                                   unsigned long long* __restrict__ st) {
    __shared__ unsigned lds[256];
    __shared__ unsigned s_exc;
    int b = blockIdx.x, t = threadIdx.x;
    int i = b * 256 + t;
    unsigned v = SC[i];
    lds[t] = v;
    __syncthreads();
    #pragma unroll
    for (int d = 1; d < 256; d <<= 1) {                 // Hillis-Steele inclusive
        unsigned add = (t >= d) ? lds[t - d] : 0;
        __syncthreads();
        lds[t] += add;
        __syncthreads();
    }
    unsigned aggregate = lds[255];
    if (t == 0) {
        unsigned long long val = (b == 0) ? ((2ull << 32) | aggregate)
                                          : ((1ull << 32) | aggregate);
        __atomic_store_n(&st[b], val, __ATOMIC_RELAXED);
    }
    if (b > 0) {
        if (t < 64) {                                   // wave-0 windowed lookback
            unsigned run = 0;
            int p = b - 1;
            for (;;) {
                int idx = p - t;                        // lane 0 = closest pred
                unsigned f, val;
                unsigned long long m2, m0;
                int l2;
                for (;;) {                              // retry until consistent
                    if (idx >= 0) {
                        unsigned long long w =
                            __atomic_load_n(&st[idx], __ATOMIC_RELAXED);
                        f = (unsigned)(w >> 32);
                        val = (unsigned)w;
                    } else { f = 2u; val = 0u; }
                    m2 = __ballot(f == 2u);
                    m0 = __ballot(f == 0u);
                    l2 = (m2 != 0ull) ? (__ffsll((long long)m2) - 1) : 64;
                    unsigned long long below =
                        (l2 >= 64) ? ~0ull : ((1ull << l2) - 1ull);
                    if ((m0 & below) == 0ull) break;    // window consistent
                }
                unsigned contrib = (t <= l2 && idx >= 0) ? val : 0u;
                #pragma unroll
                for (int s = 32; s > 0; s >>= 1)
                    contrib += __shfl_xor(contrib, s, 64);
                run += contrib;                         // uniform across lanes
                if (l2 < 64) break;                     // hit an inclusive prefix
                p -= 64;
            }
            if (t == 0) {
                s_exc = run;
                __atomic_store_n(&st[b], (2ull << 32) | (run + aggregate),
                                 __ATOMIC_RELAXED);
            }
        }
        __syncthreads();
    }
    unsigned exc = (b == 0) ? 0u : s_exc;
    SC[i] = exc + lds[t] - v;                           // global exclusive
}

// ---------------------------------------------------------------------------
// place: bucket-sorted arrays via exclusive positions (LDS cursors only).
// sp u32 = src | (dl<<16) (src<2^16, dl<49), sw = f16 weight.
// ---------------------------------------------------------------------------
__global__ __launch_bounds__(256) void place_kernel(const int* __restrict__ ei,
                                                    const float* __restrict__ ew,
                                                    const unsigned* __restrict__ SC,
                                                    unsigned* __restrict__ sp,
                                                    _Float16* __restrict__ sw) {
    __shared__ unsigned lbase[NBUK];
    __shared__ unsigned lcur[NBUK];
    int blk = blockIdx.x;
    for (int i = threadIdx.x; i < NBUK; i += 256) {
        lbase[i] = SC[i * NBBIN + blk];
        lcur[i] = 0;
    }
    __syncthreads();
    int base = blk * EBLK;
    int lim = NE - base; if (lim > EBLK) lim = EBLK;
    for (int k = threadIdx.x; k < lim; k += 256) {
        int e = base + k;
        unsigned dst = (unsigned)ei[NE + e];
        unsigned buk = dst / BUCKN;
        unsigned dl  = dst - buk * BUCKN;
        unsigned r = atomicAdd(&lcur[buk], 1u);         // LDS atomic only
        unsigned pos = lbase[buk] + r;
        sp[pos] = (unsigned)ei[e] | (dl << 16);
        sw[pos] = (_Float16)ew[e];
    }
}

// ---------------------------------------------------------------------------
// sort2: one block per bucket. 49-bin LDS histogram + rank -> node-sorted
// packed edges pw[] = src | (f16-weight-bits << 16), and per-node off[].
// ---------------------------------------------------------------------------
__global__ __launch_bounds__(256) void sort2_kernel(const unsigned* __restrict__ SC,
                                                    const unsigned* __restrict__ sp,
                                                    const _Float16* __restrict__ sw,
                                                    unsigned* __restrict__ pw,
                                                    int* __restrict__ off) {
    __shared__ unsigned hist[BUCKN], nbase[BUCKN], cur[BUCKN];
    int b = blockIdx.x;
    unsigned start = SC[b * NBBIN];
    unsigned end   = (b + 1 < NBUK) ? SC[(b + 1) * NBBIN] : NE;
    int cnt = (int)(end - start);
    if (threadIdx.x < BUCKN) { hist[threadIdx.x] = 0; cur[threadIdx.x] = 0; }
    __syncthreads();
    for (int k = threadIdx.x; k < cnt; k += 256)
        atomicAdd(&hist[sp[start + k] >> 16], 1u);      // LDS atomic
    __syncthreads();
    if (threadIdx.x == 0) {                             // tiny serial scan (49)
        unsigned run = 0;
        for (int i = 0; i < BUCKN; ++i) { nbase[i] = run; run += hist[i]; }
    }
    __syncthreads();
    if (threadIdx.x < BUCKN)
        off[b * BUCKN + threadIdx.x] = (int)(start + nbase[threadIdx.x]);
    for (int k = threadIdx.x; k < cnt; k += 256) {
        unsigned v = sp[start + k];
        unsigned dl = v >> 16;
        unsigned r = atomicAdd(&cur[dl], 1u);           // LDS atomic
        h2u c; c.f = sw[start + k];
        pw[start + nbase[dl] + r] = (v & 0xFFFFu) | ((unsigned)c.u << 16);
    }
}

// ---------------------------------------------------------------------------
// aggr: one wave per node. Lane = CHANNEL PAIR (c -> d=2c,2c+1, u32 gather);
// wave halves (h = lane>>5) process even/odd edges. One dependent round now
// covers 16 edges with 8 in-flight u32 gathers (depth-16 latency effect at
// depth-8 register cost; half the gather instructions of the 2B/lane form).
// acc += (float)f16 * f32w pairs -> v_fma_mix_f32, full f32 accumulation.
// Cross-parity combine: one shfl_xor(32) per acc; low half stores 4B/lane.
// ---------------------------------------------------------------------------
__global__ __launch_bounds__(256) void aggr_kernel(const int* __restrict__ off,
                                                   const unsigned* __restrict__ pw,
                                                   const _Float16* __restrict__ xh,
                                                   _Float16* __restrict__ aggrh) {
    int wv = (blockIdx.x * 256 + threadIdx.x) >> 6;
    if (wv >= NN) return;
    int lane = threadIdx.x & 63;
    int h = lane >> 5;                                  // edge parity
    int c = lane & 31;                                  // channel pair
    int s = off[wv], e = off[wv + 1];
    int n = e - s;
    const unsigned* p = pw + s;
    float acc0 = 0.f, acc1 = 0.f;
    for (int i = 0; i < n; i += 16) {
        unsigned P[8];
        #pragma unroll
        for (int j = 0; j < 8; ++j) {
            int idx = i + 2 * j + h;
            P[j] = p[idx < n ? idx : n - 1];            // clamped, n>=1 in loop
        }
        unsigned V[8];
        #pragma unroll
        for (int j = 0; j < 8; ++j)
            V[j] = *(const unsigned*)(xh + (P[j] & 0xFFFFu) * DD + c * 2);
        #pragma unroll
        for (int j = 0; j < 8; ++j) {
            int idx = i + 2 * j + h;
            h2u wu; wu.u = (unsigned short)(P[j] >> 16);
            float wf = (idx < n) ? (float)wu.f : 0.f;
            h2u lo, hi;
            lo.u = (unsigned short)(V[j] & 0xFFFFu);
            hi.u = (unsigned short)(V[j] >> 16);
            acc0 += (float)lo.f * wf;                   // v_fma_mix_f32
            acc1 += (float)hi.f * wf;
        }
    }
    acc0 += __shfl_xor(acc0, 32, 64);                   // merge edge parities
    acc1 += __shfl_xor(acc1, 32, 64);
    if (h == 0) {
        f16x2 o = { (_Float16)acc0, (_Float16)acc1 };
        *(f16x2*)(aggrh + wv * DD + c * 2) = o;
    }
}

// ---------------------------------------------------------------------------
// Fused GRU cell with fp16 MFMA. One wave per 16-node tile.
// A/B fragments use the SAME k mapping (8 contiguous per lane) -> result exact
// under any HW per-lane k permutation. C/D: col=lane&15, row=(lane>>4)*4+reg.
// ---------------------------------------------------------------------------
__global__ __launch_bounds__(256) void gru_kernel(
    const _Float16* __restrict__ aggrh,  // [N,64] fp16 (from aggregation)
    const _Float16* __restrict__ hA,     // [N,64] fp16: h (x or h1)
    const _Float16* __restrict__ wih,    // [192*64] fp16
    const _Float16* __restrict__ whh,    // [192*64] fp16
    const float* __restrict__ bih, const float* __restrict__ bhh,
    float* __restrict__ outF,            // layer2: d_out f32 (or null)
    _Float16* __restrict__ outH)         // layer1: h1 fp16 (or null)
{
    // Weights in LDS, rows padded 64->72 halves (144B: 16B-aligned, 2-way banks = free)
    __shared__ _Float16 W[2 * 192 * 72];
    #pragma unroll
    for (int it = 0; it < 12; ++it) {
        int idx = threadIdx.x + it * 256;          // 3072 vec8 = 2 mats * 192 rows * 8
        int mat = idx >= 1536 ? 1 : 0;
        int lid = idx - mat * 1536;
        int o = lid >> 3, k8 = (lid & 7) << 3;
        f16x8 v = *(const f16x8*)((mat ? whh : wih) + o * 64 + k8);
        *(f16x8*)&W[mat * 13824 + o * 72 + k8] = v;
    }
    __syncthreads();

    int lane = threadIdx.x & 63;
    int tile = blockIdx.x * 4 + (threadIdx.x >> 6);
    if (tile >= NT) return;
    int base = tile << 4;
    int c = lane & 15, g = lane >> 4;

    // A fragments: lane holds row (base+c), k = s*32 + g*8 .. +7
    f16x8 Aa[2], Ah[2];
    {
        const _Float16* ap = aggrh + (base + c) * DD + g * 8;
        const _Float16* hp = hA    + (base + c) * DD + g * 8;
        #pragma unroll
        for (int s = 0; s < 2; ++s) {
            Aa[s] = *(const f16x8*)(ap + s * 32);
            Ah[s] = *(const f16x8*)(hp + s * 32);
        }
    }

    f32x4 acc[12], hn[4];
    #pragma unroll
    for (int t = 0; t < 12; ++t) acc[t] = f32x4{0.f, 0.f, 0.f, 0.f};
    #pragma unroll
    for (int t = 0; t < 4; ++t) hn[t] = f32x4{0.f, 0.f, 0.f, 0.f};

    // gi for all 12 out-tiles (o = t*16+c)
    #pragma unroll
    for (int t = 0; t < 12; ++t) {
        #pragma unroll
        for (int s = 0; s < 2; ++s) {
            f16x8 b = *(const f16x8*)&W[(t * 16 + c) * 72 + s * 32 + g * 8];
            acc[t] = __builtin_amdgcn_mfma_f32_16x16x32_f16(Aa[s], b, acc[t], 0, 0, 0);
        }
    }
    // gh for r,z tiles (0..7): accumulate into the same acc (only sum needed)
    #pragma unroll
    for (int t = 0; t < 8; ++t) {
        #pragma unroll
        for (int s = 0; s < 2; ++s) {
            f16x8 b = *(const f16x8*)&W[13824 + (t * 16 + c) * 72 + s * 32 + g * 8];
            acc[t] = __builtin_amdgcn_mfma_f32_16x16x32_f16(Ah[s], b, acc[t], 0, 0, 0);
        }
    }
    // gh for n tiles (8..11): separate h_n
    #pragma unroll
    for (int t = 0; t < 4; ++t) {
        #pragma unroll
        for (int s = 0; s < 2; ++s) {
            f16x8 b = *(const f16x8*)&W[13824 + ((t + 8) * 16 + c) * 72 + s * 32 + g * 8];
            hn[t] = __builtin_amdgcn_mfma_f32_16x16x32_f16(Ah[s], b, hn[t], 0, 0, 0);
        }
    }

    // biases (lane-local, d = j*16 + c)
    float br[4], bz[4], bi_[4], bh_[4];
    #pragma unroll
    for (int j = 0; j < 4; ++j) {
        int d = j * 16 + c;
        br[j] = bih[d] + bhh[d];
        bz[j] = bih[64 + d] + bhh[64 + d];
        bi_[j] = bih[128 + d];
        bh_[j] = bhh[128 + d];
    }

    // gates + output. C layout: row (node) = g*4+m, col (d-slot) = c.
    #pragma unroll
    for (int m = 0; m < 4; ++m) {
        int n = base + g * 4 + m;
        #pragma unroll
        for (int j = 0; j < 4; ++j) {
            int d = j * 16 + c;
            float rv = 1.f / (1.f + __expf(-(acc[j][m] + br[j])));
            float zv = 1.f / (1.f + __expf(-(acc[4 + j][m] + bz[j])));
            float nv = tanhf(acc[8 + j][m] + bi_[j] + rv * (hn[j][m] + bh_[j]));
            float hold = (float)hA[n * DD + d];
            float o = (1.f - zv) * nv + zv * hold;
            if (outF) outF[n * DD + d] = o;
            else      outH[n * DD + d] = (_Float16)o;
        }
    }
}

// ---------------------------------------------------------------------------
extern "C" void kernel_launch(void* const* d_in, const int* in_sizes, int n_in,
                              void* d_out, int out_size, void* d_ws, size_t ws_size,
                              hipStream_t stream) {
    const float* x    = (const float*)d_in[0];
    const int*   ei   = (const int*)d_in[1];     // [2,E] int32
    const float* ew   = (const float*)d_in[2];   // [E,1]
    const float* wih1 = (const float*)d_in[3];
    const float* whh1 = (const float*)d_in[4];
    const float* bih1 = (const float*)d_in[5];
    const float* bhh1 = (const float*)d_in[6];
    const float* wih2 = (const float*)d_in[7];
    const float* whh2 = (const float*)d_in[8];
    const float* bih2 = (const float*)d_in[9];
    const float* bhh2 = (const float*)d_in[10];
    float* out = (float*)d_out;

    // workspace (total ~22.7MB). aggrh ALIASES the sp/sw/SC/st pool —
    // those are dead once sort2 completes (stream order).
    char* ws = (char*)d_ws;
    _Float16* xh    = (_Float16*)ws;
    _Float16* h1h   = (_Float16*)(ws + 6400000);
    unsigned* pw    = (unsigned*)(ws + 12800000);
    unsigned* sp    = (unsigned*)(ws + 16000000);
    _Float16* sw    = (_Float16*)(ws + 19200000);
    unsigned* SC    = (unsigned*)(ws + 20800000);
    unsigned long long* st = (unsigned long long*)(ws + 21602816);  // 784 x 8B
    _Float16* aggrh = (_Float16*)(ws + 16000000);   // alias: live after sort2
    _Float16* wh    = (_Float16*)(ws + 22400000);
    int*      off   = (int*)     (ws + 22498304);

    // convert (x + weights -> fp16) || per-block bucket histogram (+st zero)
    prep_kernel<<<CONVB + NBBIN, 256, 0, stream>>>(x, wih1, whh1, wih2, whh2,
                                                   xh, wh, ei, SC, st);
    // single-kernel decoupled-lookback exclusive scan of SC (in-place)
    scan_kernel<<<NSB, 256, 0, stream>>>(SC, st);
    // bucket-sorted placement, then within-bucket node sort -> pw/off
    place_kernel<<<NBBIN, 256, 0, stream>>>(ei, ew, SC, sp, sw);
    sort2_kernel<<<NBUK, 256, 0, stream>>>(SC, sp, sw, pw, off);

    // ---- layer 1 ----
    aggr_kernel<<<NN * 64 / 256, 256, 0, stream>>>(off, pw, xh, aggrh);
    gru_kernel<<<(NT + 3) / 4, 256, 0, stream>>>(aggrh, xh,
                                                 wh, wh + 12288, bih1, bhh1,
                                                 nullptr, h1h);

    // ---- layer 2 ----
    aggr_kernel<<<NN * 64 / 256, 256, 0, stream>>>(off, pw, h1h, aggrh);
    gru_kernel<<<(NT + 3) / 4, 256, 0, stream>>>(aggrh, h1h,
                                                 wh + 2 * 12288, wh + 3 * 12288, bih2, bhh2,
                                                 out, nullptr);
}